// Round 1
// baseline (1772.361 us; speedup 1.0000x reference)
//
#include <hip/hip_runtime.h>

#define GRID 64
#define NVOX (GRID * GRID * GRID)      // 262144
#define VOX_PER_BLOCK 1024
#define NBLK (NVOX / VOX_PER_BLOCK)    // 256

struct Ws {
    int   counts[NVOX];        // 1 MB
    float sums[NVOX * 7];      // 7 MB
    int   blockSums[NBLK];
    int   blockOffs[NBLK];
    int   nUnique;
};

// ---------------- scatter: atomics into per-voxel count/sum table -----------
__global__ void dv_scatter(const float* __restrict__ points,
                           const int* __restrict__ gi,
                           int n, Ws* __restrict__ ws) {
    int i = blockIdx.x * blockDim.x + threadIdx.x;
    if (i >= n) return;
    int g0 = gi[3 * i + 0];
    int g1 = gi[3 * i + 1];
    int g2 = gi[3 * i + 2];
    int lin = (g0 << 12) | (g1 << 6) | g2;
    atomicAdd(&ws->counts[lin], 1);
    const float* p = points + (size_t)i * 7;
    float* s = ws->sums + (size_t)lin * 7;
#pragma unroll
    for (int j = 0; j < 7; ++j) atomicAdd(&s[j], p[j]);
}

// ---------------- per-block occupancy sums ----------------------------------
__global__ void dv_blocksum(Ws* __restrict__ ws) {
    int b = blockIdx.x, t = threadIdx.x;
    int base = b * VOX_PER_BLOCK + t * 4;
    int c = 0;
#pragma unroll
    for (int j = 0; j < 4; ++j) c += (ws->counts[base + j] > 0) ? 1 : 0;
    __shared__ int sm[256];
    sm[t] = c;
    __syncthreads();
    for (int off = 128; off > 0; off >>= 1) {
        if (t < off) sm[t] += sm[t + off];
        __syncthreads();
    }
    if (t == 0) ws->blockSums[b] = sm[0];
}

// ---------------- exclusive scan of 256 block sums (one block) --------------
__global__ void dv_scanblocks(Ws* __restrict__ ws) {
    __shared__ int sm[NBLK];
    int t = threadIdx.x;
    int mine = ws->blockSums[t];
    sm[t] = mine;
    __syncthreads();
    for (int off = 1; off < NBLK; off <<= 1) {
        int v = (t >= off) ? sm[t - off] : 0;
        __syncthreads();
        sm[t] += v;
        __syncthreads();
    }
    ws->blockOffs[t] = sm[t] - mine;   // exclusive
    if (t == NBLK - 1) ws->nUnique = sm[t];
}

// ---------------- emit compacted means + coords -----------------------------
__global__ void dv_emit(Ws* __restrict__ ws,
                        float* __restrict__ out_mean,
                        float* __restrict__ out_coords) {
    int b = blockIdx.x, t = threadIdx.x;
    int base = b * VOX_PER_BLOCK + t * 4;
    int c[4], pre[4];
    int mycount = 0;
#pragma unroll
    for (int j = 0; j < 4; ++j) {
        c[j] = ws->counts[base + j];
        pre[j] = mycount;
        mycount += (c[j] > 0) ? 1 : 0;
    }
    __shared__ int sm[256];
    sm[t] = mycount;
    __syncthreads();
    for (int off = 1; off < 256; off <<= 1) {
        int v = (t >= off) ? sm[t - off] : 0;
        __syncthreads();
        sm[t] += v;
        __syncthreads();
    }
    int rank0 = ws->blockOffs[b] + (sm[t] - mycount);
#pragma unroll
    for (int j = 0; j < 4; ++j) {
        if (c[j] > 0) {
            int r = rank0 + pre[j];
            int v = base + j;
            float inv = 1.0f / (float)c[j];
            float* m = out_mean + (size_t)r * 7;
            const float* s = ws->sums + (size_t)v * 7;
#pragma unroll
            for (int k = 0; k < 7; ++k) m[k] = s[k] * inv;
            float* cd = out_coords + (size_t)r * 3;
            cd[0] = (float)(v >> 12);
            cd[1] = (float)((v >> 6) & 63);
            cd[2] = (float)(v & 63);
        }
    }
}

// ---------------- fill padding rows (out is re-poisoned every call) ---------
__global__ void dv_fill(const Ws* __restrict__ ws,
                        float* __restrict__ out_mean,
                        float* __restrict__ out_coords, int n) {
    int i = blockIdx.x * blockDim.x + threadIdx.x;
    if (i >= n) return;
    int nu = ws->nUnique;
    if (i < nu) return;
    float* m = out_mean + (size_t)i * 7;
#pragma unroll
    for (int k = 0; k < 7; ++k) m[k] = 0.0f;
    float* cd = out_coords + (size_t)i * 3;
    cd[0] = -1.0f;
    cd[1] = -1.0f;
    cd[2] = -1.0f;
}

extern "C" void kernel_launch(void* const* d_in, const int* in_sizes, int n_in,
                              void* d_out, int out_size, void* d_ws, size_t ws_size,
                              hipStream_t stream) {
    const float* points = (const float*)d_in[0];
    const int*   gi     = (const int*)d_in[1];
    int n = in_sizes[0] / 7;   // 4,000,000

    Ws* ws = (Ws*)d_ws;
    float* out_mean   = (float*)d_out;                   // [n, 7]
    float* out_coords = (float*)d_out + (size_t)n * 7;   // [n, 3]

    hipMemsetAsync(d_ws, 0, sizeof(Ws), stream);

    int threads = 256;
    int blocksN = (n + threads - 1) / threads;
    dv_scatter<<<blocksN, threads, 0, stream>>>(points, gi, n, ws);
    dv_blocksum<<<NBLK, 256, 0, stream>>>(ws);
    dv_scanblocks<<<1, NBLK, 0, stream>>>(ws);
    dv_emit<<<NBLK, 256, 0, stream>>>(ws, out_mean, out_coords);
    dv_fill<<<blocksN, threads, 0, stream>>>(ws, out_mean, out_coords, n);
}